// Round 14
// baseline (146.043 us; speedup 1.0000x reference)
//
#include <hip/hip_runtime.h>

#define B 8
#define T 512
#define P 2048
#define D 768
#define KDIM P
#define NSPLIT 2
#define KSPLIT (KDIM / NSPLIT)   // 1024 = 16 K-steps of 64

typedef unsigned short ushort_t;
using short8 = __attribute__((ext_vector_type(8))) short;
using f32x4v = __attribute__((ext_vector_type(4))) float;

// ws float-index layout
#define IDX_SCALE 0
#define IDX_SCORES 64                    // B*P floats (z=0 partial in main path; full in fallback)
#define IDX_SCORES2 (64 + B*P)           // z=1 partials (main path) — aliases IDX_CX (fallback-only)
#define IDX_CX (64 + B*P)                // fallback path only
#define IDX_CY (64 + 2*B*P)              // fallback path only
#define OFF_ATTN_BYTES 197120            // past float region (196,864 B), 256-aligned
#define OFF_FT_BYTES (OFF_ATTN_BYTES + (size_t)B*T*P*2)
#define OFF_PART_BYTES (OFF_FT_BYTES + (size_t)B*D*P*2)
#define OFF_CTR_BYTES (OFF_PART_BYTES + (size_t)NSPLIT*B*T*D*2)
#define NTILES (B * (T/128) * (D/128))   // 192 output tiles
#define WS_NEED (OFF_CTR_BYTES + (size_t)NTILES*4)

#define GLD16(gsrc, ldst) \
    __builtin_amdgcn_global_load_lds((const __attribute__((address_space(1))) void*)(gsrc), \
                                     (__attribute__((address_space(3))) void*)(ldst), 16, 0, 0)

#define SCHED_FENCE() __builtin_amdgcn_sched_barrier(0)
#define RAW_BARRIER() do { SCHED_FENCE(); __builtin_amdgcn_s_barrier(); SCHED_FENCE(); } while (0)

__device__ inline ushort_t f2bf(float x) {
    union { float f; unsigned u; } v; v.f = x;
    unsigned r = v.u + 0x7fffu + ((v.u >> 16) & 1u);
    return (ushort_t)(r >> 16);
}
__device__ inline float bf2f(ushort_t u) {
    return __uint_as_float(((unsigned)u) << 16);
}

// fallback-path only
__global__ void k_scale(const float* __restrict__ tboxes, float* __restrict__ ws) {
    __shared__ float red[4];
    int tid = threadIdx.x;
    float m = -1e30f;
    const float4* tb4 = (const float4*)tboxes;
    #pragma unroll
    for (int i = 0; i < 16; ++i) {
        float4 v = tb4[tid + i * 256];
        m = fmaxf(fmaxf(fmaxf(m, v.x), fmaxf(v.y, v.z)), v.w);
    }
    #pragma unroll
    for (int off = 1; off < 64; off <<= 1) m = fmaxf(m, __shfl_xor(m, off));
    if ((tid & 63) == 0) red[tid >> 6] = m;
    __syncthreads();
    if (tid == 0) {
        float mb = fmaxf(fmaxf(red[0], red[1]), fmaxf(red[2], red[3]));
        ws[IDX_SCALE] = (mb > 1.5f) ? (1.0f / 1000.0f) : 1.0f;
    }
}

// Fused: partial scores (D-half) + fT transpose + (block 0,0,0) scale + (block 1,0,0) ctr zero.
__global__ __launch_bounds__(256) void k_prep(const float* __restrict__ feats,
        const float* __restrict__ w, const float* __restrict__ tboxes,
        float* __restrict__ ws, ushort_t* __restrict__ fT, int* __restrict__ ctr) {
    __shared__ float tile[2][64][65];
    __shared__ float sred[64][17];
    const int t = threadIdx.x;
    const int p0 = blockIdx.x * 64;
    const int z = blockIdx.y;
    const int b = blockIdx.z;

    // side-jobs
    if (blockIdx.x == 1 && z == 0 && b == 0 && t < NTILES) ctr[t] = 0;
    if (blockIdx.x == 0 && z == 0 && b == 0) {
        __shared__ float red[4];
        float m = -1e30f;
        const float4* tb4 = (const float4*)tboxes;
        #pragma unroll
        for (int i = 0; i < 16; ++i) {
            float4 v = tb4[t + i * 256];
            m = fmaxf(fmaxf(fmaxf(m, v.x), fmaxf(v.y, v.z)), v.w);
        }
        #pragma unroll
        for (int off = 1; off < 64; off <<= 1) m = fmaxf(m, __shfl_xor(m, off));
        if ((t & 63) == 0) red[t >> 6] = m;
        __syncthreads();
        if (t == 0) {
            float mb = fmaxf(fmaxf(red[0], red[1]), fmaxf(red[2], red[3]));
            ws[IDX_SCALE] = (mb > 1.5f) ? (1.0f / 1000.0f) : 1.0f;
        }
        __syncthreads();
    }

    const float4* f4 = (const float4*)(feats + ((size_t)b * P + p0) * D);
    const float4* w4 = (const float4*)w;
    const int tr = t >> 4, tc = t & 15;
    float sp[4] = {0.f, 0.f, 0.f, 0.f};

    float4 v[4];
    {
        int dt = z * 6;
        #pragma unroll
        for (int i = 0; i < 4; ++i)
            v[i] = f4[(size_t)(tr + 16 * i) * 192 + dt * 16 + tc];
    }
    int cur = 0;
    for (int it = 0; it < 6; ++it) {
        const int dt = z * 6 + it;
        float4 wv = w4[dt * 16 + tc];
        #pragma unroll
        for (int i = 0; i < 4; ++i) {
            int pr = tr + 16 * i;
            sp[i] += v[i].x * wv.x + v[i].y * wv.y + v[i].z * wv.z + v[i].w * wv.w;
            tile[cur][pr][tc * 4 + 0] = v[i].x;
            tile[cur][pr][tc * 4 + 1] = v[i].y;
            tile[cur][pr][tc * 4 + 2] = v[i].z;
            tile[cur][pr][tc * 4 + 3] = v[i].w;
        }
        __syncthreads();
        if (it < 5) {
            int dt2 = dt + 1;
            #pragma unroll
            for (int i = 0; i < 4; ++i)
                v[i] = f4[(size_t)(tr + 16 * i) * 192 + dt2 * 16 + tc];
        }
        #pragma unroll
        for (int pass = 0; pass < 4; ++pass) {
            int idx = pass * 256 + t;
            int dr = idx >> 4;
            int pq = (idx & 15) * 4;
            unsigned u0 = (unsigned)f2bf(tile[cur][pq + 0][dr]) |
                          ((unsigned)f2bf(tile[cur][pq + 1][dr]) << 16);
            unsigned u1 = (unsigned)f2bf(tile[cur][pq + 2][dr]) |
                          ((unsigned)f2bf(tile[cur][pq + 3][dr]) << 16);
            uint2 o; o.x = u0; o.y = u1;
            *(uint2*)&fT[((size_t)b * D + dt * 64 + dr) * P + p0 + pq] = o;
        }
        cur ^= 1;
    }
    #pragma unroll
    for (int i = 0; i < 4; ++i) sred[tr + 16 * i][tc] = sp[i];
    __syncthreads();
    if (t < 64) {
        float s = 0.f;
        #pragma unroll
        for (int c = 0; c < 16; ++c) s += sred[t][c];
        ws[(z ? IDX_SCORES2 : IDX_SCORES) + b * P + p0 + t] = s;
    }
}

// wave-per-token softmax: no barriers, no LDS. 4 waves/block, grid (T/4, B).
__global__ __launch_bounds__(256) void k_attn(const float* __restrict__ tboxes,
        const float* __restrict__ pboxes, const unsigned char* __restrict__ mask8,
        const float* __restrict__ bias, const float* __restrict__ ws,
        ushort_t* __restrict__ attn, float* __restrict__ out) {
    const int wv = threadIdx.x >> 6;
    const int ln = threadIdx.x & 63;
    const int t = blockIdx.x * 4 + wv;
    const int b = blockIdx.y;
    const int row = b * T + t;
    const float scale = ws[IDX_SCALE];
    const float bs = bias[0];
    const float4 tb = ((const float4*)tboxes)[row];
    const float lox = tb.x * scale, loy = tb.y * scale;
    const float hix = tb.z * scale, hiy = tb.w * scale;
    bool storage_u8 = ((mask8[1] | mask8[2] | mask8[3]) != 0);
    bool tmask = storage_u8 ? (mask8[row] != 0) : (((const int*)mask8)[row] != 0);

    const float2* sA = (const float2*)(ws + IDX_SCORES + b * P);
    const float2* sB = (const float2*)(ws + IDX_SCORES2 + b * P);
    const float4* pb4 = (const float4*)(pboxes + (size_t)b * P * 4);
    unsigned* arow32 = (unsigned*)(attn + (size_t)row * P);

    float s0[16], s1[16];
    float m = -1e30f;
    const float NINF = -__builtin_inff();
    #pragma unroll
    for (int r = 0; r < 16; ++r) {
        int q = ln + 64 * r;
        float2 sa = sA[q], sb = sB[q];
        float v0 = sa.x + sb.x + bs;
        float v1 = sa.y + sb.y + bs;
        float4 b0 = pb4[2 * q], b1 = pb4[2 * q + 1];
        float cx0 = 0.5f * (b0.x + b0.z), cy0 = 0.5f * (b0.y + b0.w);
        float cx1 = 0.5f * (b1.x + b1.z), cy1 = 0.5f * (b1.y + b1.w);
        bool i0 = (cx0 >= lox) && (cx0 <= hix) && (cy0 >= loy) && (cy0 <= hiy);
        bool i1 = (cx1 >= lox) && (cx1 <= hix) && (cy1 >= loy) && (cy1 <= hiy);
        s0[r] = i0 ? v0 : NINF;
        s1[r] = i1 ? v1 : NINF;
        m = fmaxf(m, fmaxf(s0[r], s1[r]));
    }
    #pragma unroll
    for (int off = 1; off < 64; off <<= 1) m = fmaxf(m, __shfl_xor(m, off));
    bool any = m > -1e29f;

    if (!any || !tmask) {
        #pragma unroll
        for (int r = 0; r < 16; ++r) arow32[ln + 64 * r] = 0u;
        if (ln == 0) out[(size_t)B * T * D + row] = 0.f;
        return;
    }
    float lsum = 0.f;
    #pragma unroll
    for (int r = 0; r < 16; ++r) {
        s0[r] = __expf(s0[r] - m);
        s1[r] = __expf(s1[r] - m);
        lsum += s0[r] + s1[r];
    }
    #pragma unroll
    for (int off = 1; off < 64; off <<= 1) lsum += __shfl_xor(lsum, off);
    float invl = 1.0f / lsum;
    #pragma unroll
    for (int r = 0; r < 16; ++r) {
        unsigned lo = (unsigned)f2bf(s0[r] * invl);
        unsigned hi = (unsigned)f2bf(s1[r] * invl);
        arow32[ln + 64 * r] = lo | (hi << 16);
    }
    if (ln == 0) out[(size_t)B * T * D + row] = 1.0f;
}

// Split-K GEMM with finisher-block reduce fusion. R13 loop structure (proven):
// BM=128, BN=128, BK=64; 4 waves (2x2); depth-2 counted-vmcnt dbuf (64KB LDS).
// Each block: acc -> bf16, write own partial, fence, atomicAdd(ctr); second arriver
// reads the OTHER split's (L2-warm) partial at its fragment positions and writes out.
// Deterministic: both operands bf16-rounded; f32 add commutative.
__global__ __launch_bounds__(256, 2) void k_gemm(const ushort_t* __restrict__ attn,
        const ushort_t* __restrict__ fT, ushort_t* __restrict__ partial,
        int* __restrict__ ctr, float* __restrict__ out) {
    __shared__ __align__(16) ushort_t As[2 * 8192];
    __shared__ __align__(16) ushort_t Bs[2 * 8192];
    __shared__ int s_old;
    const int tid = threadIdx.x;
    const int lane = tid & 63, wid = tid >> 6;      // wid 0..3
    const int wm = wid >> 1, wn = wid & 1;          // 2 x 2 wave grid

    const int bid = blockIdx.x;
    const int g = bid & 7;                          // XCD group
    const int i6 = bid >> 3;                        // 0..47
    const int tq = g & 3;                           // t-quadrant
    const int s = g >> 2;                           // K-half
    const int b = i6 & 7;
    const int n0 = (i6 >> 3) * 128;                 // 0..5
    const int t0 = tq * 128;
    const int kbase = s * KSPLIT;
    const int cid = b * 24 + tq * 6 + (i6 >> 3);    // output-tile counter id

    const ushort_t* Ab = attn + ((size_t)b * T + t0) * P + kbase;
    const ushort_t* Bb = fT + ((size_t)b * D + n0) * P + kbase;

    const int rl8 = lane >> 3;               // row within 8-row chunk
    const int slot = (lane & 7) ^ rl8;       // pre-swizzled 16B slot in global row

    f32x4v acc[4][4];
    #pragma unroll
    for (int i = 0; i < 4; ++i)
        #pragma unroll
        for (int j = 0; j < 4; ++j)
            acc[i][j] = (f32x4v){0.f, 0.f, 0.f, 0.f};

    const int lr = lane & 15, hi4 = lane >> 4;

    #define STAGE(buf, kt) do { \
        const ushort_t* a_src = Ab + (size_t)(kt) * 64; \
        const ushort_t* b_src = Bb + (size_t)(kt) * 64; \
        _Pragma("unroll") \
        for (int i = 0; i < 4; ++i) { \
            int c = wid * 4 + i; \
            GLD16(a_src + (size_t)(c * 8 + rl8) * P + slot * 8, &As[(buf) * 8192 + c * 512]); \
        } \
        _Pragma("unroll") \
        for (int i = 0; i < 4; ++i) { \
            int c = wid * 4 + i; \
            GLD16(b_src + (size_t)(c * 8 + rl8) * P + slot * 8, &Bs[(buf) * 8192 + c * 512]); \
        } \
    } while (0)

    // swizzled LDS read address (ushort units) for (row, 16B-slot kslot)
    #define LDA(row, kslot) (((row) >> 3) * 512 + ((row) & 7) * 64 + (((kslot) ^ ((row) & 7)) * 8))

    #define COMPUTE(buf) do { \
        _Pragma("unroll") \
        for (int ks = 0; ks < 2; ++ks) { \
            short8 a[4], bfr[4]; \
            int kslot = ks * 4 + hi4; \
            _Pragma("unroll") \
            for (int i = 0; i < 4; ++i) \
                a[i] = *(const short8*)&As[(buf) * 8192 + LDA(wm * 64 + i * 16 + lr, kslot)]; \
            _Pragma("unroll") \
            for (int j = 0; j < 4; ++j) \
                bfr[j] = *(const short8*)&Bs[(buf) * 8192 + LDA(wn * 64 + j * 16 + lr, kslot)]; \
            _Pragma("unroll") \
            for (int i = 0; i < 4; ++i) \
                _Pragma("unroll") \
                for (int j = 0; j < 4; ++j) \
                    acc[i][j] = __builtin_amdgcn_mfma_f32_16x16x32_bf16(a[i], bfr[j], acc[i][j], 0, 0, 0); \
        } \
    } while (0)

    STAGE(0, 0);
    int cur = 0;
    for (int kt = 0; kt < KSPLIT / 64 - 1; ++kt) {
        STAGE(cur ^ 1, kt + 1);
        asm volatile("s_waitcnt vmcnt(8)" ::: "memory");    // prev buffer's 8 loads retired
        RAW_BARRIER();
        COMPUTE(cur);
        RAW_BARRIER();                                      // WAR before next STAGE overwrite
        cur ^= 1;
    }
    asm volatile("s_waitcnt vmcnt(0)" ::: "memory");
    RAW_BARRIER();
    COMPUTE(cur);

    // ---- finisher-fused epilogue ----
    ushort_t myb[4][4][4];
    ushort_t* pown = partial + (size_t)s * B * T * D;
    #pragma unroll
    for (int i = 0; i < 4; ++i) {
        #pragma unroll
        for (int j = 0; j < 4; ++j) {
            int trow = t0 + wm * 64 + i * 16 + hi4 * 4;
            int ncol = n0 + wn * 64 + j * 16 + lr;
            #pragma unroll
            for (int q = 0; q < 4; ++q) {
                ushort_t v = f2bf(acc[i][j][q]);
                myb[i][j][q] = v;
                pown[((size_t)(b * T) + trow + q) * D + ncol] = v;
            }
        }
    }
    __threadfence();          // make partial visible device-wide (cross-XCD)
    __syncthreads();          // all threads' stores fenced before the atomic
    if (tid == 0) s_old = atomicAdd(&ctr[cid], 1);
    __syncthreads();
    if (s_old == 1) {
        __threadfence();      // acquire: see the other split's partial
        const ushort_t* poth = partial + (size_t)(1 - s) * B * T * D;
        #pragma unroll
        for (int i = 0; i < 4; ++i) {
            #pragma unroll
            for (int j = 0; j < 4; ++j) {
                int trow = t0 + wm * 64 + i * 16 + hi4 * 4;
                int ncol = n0 + wn * 64 + j * 16 + lr;
                #pragma unroll
                for (int q = 0; q < 4; ++q) {
                    size_t idx = ((size_t)(b * T) + trow + q) * D + ncol;
                    out[idx] = bf2f(myb[i][j][q]) + bf2f(poth[idx]);
                }
            }
        }
    }
    #undef STAGE
    #undef LDA
    #undef COMPUTE
}

// ---------------- fallback path (round-1, known-good) ----------------
__global__ __launch_bounds__(256) void k_scores_fb(
        const float* __restrict__ feats, const float* __restrict__ pboxes,
        const float* __restrict__ w, const float* __restrict__ bias,
        float* __restrict__ ws) {
    int row = blockIdx.x * 4 + (threadIdx.x >> 6);
    int lane = threadIdx.x & 63;
    const float* f = feats + (size_t)row * D;
    float acc = 0.f;
    #pragma unroll
    for (int k = 0; k < D / 64; ++k) acc += f[lane + k * 64] * w[lane + k * 64];
    #pragma unroll
    for (int off = 1; off < 64; off <<= 1) acc += __shfl_xor(acc, off);
    if (lane == 0) {
        ws[IDX_SCORES + row] = acc + bias[0];
        ws[IDX_CX + row] = 0.5f * (pboxes[row * 4 + 0] + pboxes[row * 4 + 2]);
        ws[IDX_CY + row] = 0.5f * (pboxes[row * 4 + 1] + pboxes[row * 4 + 3]);
    }
}

__global__ __launch_bounds__(256) void k_main_fb(
        const float* __restrict__ feats, const float* __restrict__ tboxes,
        const unsigned char* __restrict__ mask8,
        const float* __restrict__ ws, float* __restrict__ out) {
    const int t = blockIdx.x, b = blockIdx.y;
    const int tid = threadIdx.x;
    const float scale = ws[IDX_SCALE];
    const float* scores = ws + IDX_SCORES;
    const float* cxs = ws + IDX_CX;
    const float* cys = ws + IDX_CY;
    const int row = b * T + t;
    const float lo_x = tboxes[row * 4 + 0] * scale;
    const float lo_y = tboxes[row * 4 + 1] * scale;
    const float hi_x = tboxes[row * 4 + 2] * scale;
    const float hi_y = tboxes[row * 4 + 3] * scale;
    bool storage_u8 = ((mask8[1] | mask8[2] | mask8[3]) != 0);
    bool tmask = storage_u8 ? (mask8[row] != 0) : (((const int*)mask8)[row] != 0);
    float s[8]; bool ib[8];
    float m = -1e30f;
    #pragma unroll
    for (int j = 0; j < 8; ++j) {
        int p = tid + j * 256;
        float cx = cxs[b * P + p], cy = cys[b * P + p];
        bool in = (cx >= lo_x) && (cx <= hi_x) && (cy >= lo_y) && (cy <= hi_y);
        ib[j] = in;
        s[j] = scores[b * P + p];
        if (in) m = fmaxf(m, s[j]);
    }
    __shared__ float s_red[4];
    #pragma unroll
    for (int off = 1; off < 64; off <<= 1) m = fmaxf(m, __shfl_xor(m, off));
    if ((tid & 63) == 0) s_red[tid >> 6] = m;
    __syncthreads();
    float mb = fmaxf(fmaxf(s_red[0], s_red[1]), fmaxf(s_red[2], s_red[3]));
    bool any = mb > -1e29f;
    const size_t obase = (size_t)row * D;
    if (!any || !tmask) {
        out[obase + tid] = 0.f; out[obase + tid + 256] = 0.f; out[obase + tid + 512] = 0.f;
        if (tid == 0) out[(size_t)B * T * D + row] = 0.f;
        return;
    }
    float w8[8]; int c = 0; float lsum = 0.f;
    #pragma unroll
    for (int j = 0; j < 8; ++j) {
        float wv = ib[j] ? __expf(s[j] - mb) : 0.f;
        w8[j] = wv; lsum += wv;
        if (ib[j]) ++c;
    }
    __shared__ float s_sum[4];
    #pragma unroll
    for (int off = 1; off < 64; off <<= 1) lsum += __shfl_xor(lsum, off);
    if ((tid & 63) == 0) s_sum[tid >> 6] = lsum;
    __syncthreads();
    float l = s_sum[0] + s_sum[1] + s_sum[2] + s_sum[3];
    __shared__ int s_cnt[256];
    s_cnt[tid] = c;
    __syncthreads();
    #pragma unroll
    for (int off = 1; off < 256; off <<= 1) {
        int v = (tid >= off) ? s_cnt[tid - off] : 0;
        __syncthreads();
        s_cnt[tid] += v;
        __syncthreads();
    }
    int excl = s_cnt[tid] - c;
    int nnz = s_cnt[255];
    __shared__ int s_idx[P];
    __shared__ float s_wt[P];
    int o = excl;
    #pragma unroll
    for (int j = 0; j < 8; ++j) {
        if (ib[j]) { s_idx[o] = tid + j * 256; s_wt[o] = w8[j]; ++o; }
    }
    __syncthreads();
    float a0 = 0.f, a1 = 0.f, a2 = 0.f;
    const float* fb = feats + (size_t)b * P * D;
    for (int i = 0; i < nnz; ++i) {
        int p = s_idx[i];
        float wv = s_wt[i];
        const float* fr = fb + (size_t)p * D + tid;
        a0 += wv * fr[0]; a1 += wv * fr[256]; a2 += wv * fr[512];
    }
    float inv = 1.0f / l;
    out[obase + tid] = a0 * inv;
    out[obase + tid + 256] = a1 * inv;
    out[obase + tid + 512] = a2 * inv;
    if (tid == 0) out[(size_t)B * T * D + row] = 1.0f;
}

extern "C" void kernel_launch(void* const* d_in, const int* in_sizes, int n_in,
                              void* d_out, int out_size, void* d_ws, size_t ws_size,
                              hipStream_t stream) {
    const float* feats  = (const float*)d_in[0];
    const float* tboxes = (const float*)d_in[1];
    const float* pboxes = (const float*)d_in[2];
    const unsigned char* tmask = (const unsigned char*)d_in[3];
    const float* w      = (const float*)d_in[4];
    const float* bias   = (const float*)d_in[5];
    float* out = (float*)d_out;
    float* ws  = (float*)d_ws;

    if (ws_size >= WS_NEED) {
        ushort_t* attn = (ushort_t*)((char*)d_ws + OFF_ATTN_BYTES);
        ushort_t* fT   = (ushort_t*)((char*)d_ws + OFF_FT_BYTES);
        ushort_t* part = (ushort_t*)((char*)d_ws + OFF_PART_BYTES);
        int* ctr       = (int*)((char*)d_ws + OFF_CTR_BYTES);
        k_prep<<<dim3(P / 64, 2, B), 256, 0, stream>>>(feats, w, tboxes, ws, fT, ctr);
        k_attn<<<dim3(T / 4, B), 256, 0, stream>>>(tboxes, pboxes, tmask, bias, ws, attn, out);
        k_gemm<<<dim3(NSPLIT * B * (T / 128) * (D / 128)), 256, 0, stream>>>(attn, fT, part, ctr, out);
    } else {
        k_scale<<<1, 256, 0, stream>>>(tboxes, ws);
        k_scores_fb<<<(B * P) / 4, 256, 0, stream>>>(feats, pboxes, w, bias, ws);
        k_main_fb<<<dim3(T, B), 256, 0, stream>>>(feats, tboxes, tmask, ws, out);
    }
}

// Round 15
// 58.041 us; speedup vs baseline: 2.5162x; 2.5162x over previous
//
#include <hip/hip_runtime.h>

#define B 8
#define T 512
#define P 2048
#define D 768
#define KDIM P
#define NSPLIT 2
#define KSPLIT (KDIM / NSPLIT)   // 1024 = 16 K-steps of 64

typedef unsigned short ushort_t;
using short8 = __attribute__((ext_vector_type(8))) short;
using f32x4v = __attribute__((ext_vector_type(4))) float;

// ws float-index layout
#define IDX_SCALE 0
#define IDX_SCORES 64                    // B*P floats (z=0 partial in main path; full in fallback)
#define IDX_SCORES2 (64 + B*P)           // z=1 partials (main path) — aliases IDX_CX (fallback-only)
#define IDX_CX (64 + B*P)                // fallback path only
#define IDX_CY (64 + 2*B*P)              // fallback path only
#define OFF_ATTN_BYTES 197120            // past float region (196,864 B), 256-aligned
#define OFF_FT_BYTES (OFF_ATTN_BYTES + (size_t)B*T*P*2)
#define OFF_PART_BYTES (OFF_FT_BYTES + (size_t)B*D*P*2)
#define WS_NEED (OFF_PART_BYTES + (size_t)NSPLIT*B*T*D*2)

#define GLD16(gsrc, ldst) \
    __builtin_amdgcn_global_load_lds((const __attribute__((address_space(1))) void*)(gsrc), \
                                     (__attribute__((address_space(3))) void*)(ldst), 16, 0, 0)

#define SCHED_FENCE() __builtin_amdgcn_sched_barrier(0)
#define RAW_BARRIER() do { SCHED_FENCE(); __builtin_amdgcn_s_barrier(); SCHED_FENCE(); } while (0)

__device__ inline ushort_t f2bf(float x) {
    union { float f; unsigned u; } v; v.f = x;
    unsigned r = v.u + 0x7fffu + ((v.u >> 16) & 1u);
    return (ushort_t)(r >> 16);
}
__device__ inline float bf2f(ushort_t u) {
    return __uint_as_float(((unsigned)u) << 16);
}

// fallback-path only
__global__ void k_scale(const float* __restrict__ tboxes, float* __restrict__ ws) {
    __shared__ float red[4];
    int tid = threadIdx.x;
    float m = -1e30f;
    const float4* tb4 = (const float4*)tboxes;
    #pragma unroll
    for (int i = 0; i < 16; ++i) {
        float4 v = tb4[tid + i * 256];
        m = fmaxf(fmaxf(fmaxf(m, v.x), fmaxf(v.y, v.z)), v.w);
    }
    #pragma unroll
    for (int off = 1; off < 64; off <<= 1) m = fmaxf(m, __shfl_xor(m, off));
    if ((tid & 63) == 0) red[tid >> 6] = m;
    __syncthreads();
    if (tid == 0) {
        float mb = fmaxf(fmaxf(red[0], red[1]), fmaxf(red[2], red[3]));
        ws[IDX_SCALE] = (mb > 1.5f) ? (1.0f / 1000.0f) : 1.0f;
    }
}

// Fused: partial scores (D-half) + fT transpose + (block 0,0,0) scale side-job.
__global__ __launch_bounds__(256) void k_prep(const float* __restrict__ feats,
        const float* __restrict__ w, const float* __restrict__ tboxes,
        float* __restrict__ ws, ushort_t* __restrict__ fT) {
    __shared__ float tile[2][64][65];
    __shared__ float sred[64][17];
    const int t = threadIdx.x;
    const int p0 = blockIdx.x * 64;
    const int z = blockIdx.y;
    const int b = blockIdx.z;

    // scale side-job (overlapped with the other 511 blocks' work)
    if (blockIdx.x == 0 && z == 0 && b == 0) {
        __shared__ float red[4];
        float m = -1e30f;
        const float4* tb4 = (const float4*)tboxes;
        #pragma unroll
        for (int i = 0; i < 16; ++i) {
            float4 v = tb4[t + i * 256];
            m = fmaxf(fmaxf(fmaxf(m, v.x), fmaxf(v.y, v.z)), v.w);
        }
        #pragma unroll
        for (int off = 1; off < 64; off <<= 1) m = fmaxf(m, __shfl_xor(m, off));
        if ((t & 63) == 0) red[t >> 6] = m;
        __syncthreads();
        if (t == 0) {
            float mb = fmaxf(fmaxf(red[0], red[1]), fmaxf(red[2], red[3]));
            ws[IDX_SCALE] = (mb > 1.5f) ? (1.0f / 1000.0f) : 1.0f;
        }
        __syncthreads();
    }

    const float4* f4 = (const float4*)(feats + ((size_t)b * P + p0) * D);
    const float4* w4 = (const float4*)w;
    const int tr = t >> 4, tc = t & 15;
    float sp[4] = {0.f, 0.f, 0.f, 0.f};

    float4 v[4];
    {
        int dt = z * 6;
        #pragma unroll
        for (int i = 0; i < 4; ++i)
            v[i] = f4[(size_t)(tr + 16 * i) * 192 + dt * 16 + tc];
    }
    int cur = 0;
    for (int it = 0; it < 6; ++it) {
        const int dt = z * 6 + it;
        float4 wv = w4[dt * 16 + tc];
        #pragma unroll
        for (int i = 0; i < 4; ++i) {
            int pr = tr + 16 * i;
            sp[i] += v[i].x * wv.x + v[i].y * wv.y + v[i].z * wv.z + v[i].w * wv.w;
            tile[cur][pr][tc * 4 + 0] = v[i].x;
            tile[cur][pr][tc * 4 + 1] = v[i].y;
            tile[cur][pr][tc * 4 + 2] = v[i].z;
            tile[cur][pr][tc * 4 + 3] = v[i].w;
        }
        __syncthreads();
        if (it < 5) {
            int dt2 = dt + 1;
            #pragma unroll
            for (int i = 0; i < 4; ++i)
                v[i] = f4[(size_t)(tr + 16 * i) * 192 + dt2 * 16 + tc];
        }
        #pragma unroll
        for (int pass = 0; pass < 4; ++pass) {
            int idx = pass * 256 + t;
            int dr = idx >> 4;
            int pq = (idx & 15) * 4;
            unsigned u0 = (unsigned)f2bf(tile[cur][pq + 0][dr]) |
                          ((unsigned)f2bf(tile[cur][pq + 1][dr]) << 16);
            unsigned u1 = (unsigned)f2bf(tile[cur][pq + 2][dr]) |
                          ((unsigned)f2bf(tile[cur][pq + 3][dr]) << 16);
            uint2 o; o.x = u0; o.y = u1;
            *(uint2*)&fT[((size_t)b * D + dt * 64 + dr) * P + p0 + pq] = o;
        }
        cur ^= 1;
    }
    #pragma unroll
    for (int i = 0; i < 4; ++i) sred[tr + 16 * i][tc] = sp[i];
    __syncthreads();
    if (t < 64) {
        float s = 0.f;
        #pragma unroll
        for (int c = 0; c < 16; ++c) s += sred[t][c];
        ws[(z ? IDX_SCORES2 : IDX_SCORES) + b * P + p0 + t] = s;
    }
}

// wave-per-token softmax: no barriers, no LDS. 4 waves/block, grid (T/4, B).
__global__ __launch_bounds__(256) void k_attn(const float* __restrict__ tboxes,
        const float* __restrict__ pboxes, const unsigned char* __restrict__ mask8,
        const float* __restrict__ bias, const float* __restrict__ ws,
        ushort_t* __restrict__ attn, float* __restrict__ out) {
    const int wv = threadIdx.x >> 6;
    const int ln = threadIdx.x & 63;
    const int t = blockIdx.x * 4 + wv;
    const int b = blockIdx.y;
    const int row = b * T + t;
    const float scale = ws[IDX_SCALE];
    const float bs = bias[0];
    const float4 tb = ((const float4*)tboxes)[row];
    const float lox = tb.x * scale, loy = tb.y * scale;
    const float hix = tb.z * scale, hiy = tb.w * scale;
    bool storage_u8 = ((mask8[1] | mask8[2] | mask8[3]) != 0);
    bool tmask = storage_u8 ? (mask8[row] != 0) : (((const int*)mask8)[row] != 0);

    const float2* sA = (const float2*)(ws + IDX_SCORES + b * P);
    const float2* sB = (const float2*)(ws + IDX_SCORES2 + b * P);
    const float4* pb4 = (const float4*)(pboxes + (size_t)b * P * 4);
    unsigned* arow32 = (unsigned*)(attn + (size_t)row * P);

    float s0[16], s1[16];
    float m = -1e30f;
    const float NINF = -__builtin_inff();
    #pragma unroll
    for (int r = 0; r < 16; ++r) {
        int q = ln + 64 * r;
        float2 sa = sA[q], sb = sB[q];
        float v0 = sa.x + sb.x + bs;
        float v1 = sa.y + sb.y + bs;
        float4 b0 = pb4[2 * q], b1 = pb4[2 * q + 1];
        float cx0 = 0.5f * (b0.x + b0.z), cy0 = 0.5f * (b0.y + b0.w);
        float cx1 = 0.5f * (b1.x + b1.z), cy1 = 0.5f * (b1.y + b1.w);
        bool i0 = (cx0 >= lox) && (cx0 <= hix) && (cy0 >= loy) && (cy0 <= hiy);
        bool i1 = (cx1 >= lox) && (cx1 <= hix) && (cy1 >= loy) && (cy1 <= hiy);
        s0[r] = i0 ? v0 : NINF;
        s1[r] = i1 ? v1 : NINF;
        m = fmaxf(m, fmaxf(s0[r], s1[r]));
    }
    #pragma unroll
    for (int off = 1; off < 64; off <<= 1) m = fmaxf(m, __shfl_xor(m, off));
    bool any = m > -1e29f;

    if (!any || !tmask) {
        #pragma unroll
        for (int r = 0; r < 16; ++r) arow32[ln + 64 * r] = 0u;
        if (ln == 0) out[(size_t)B * T * D + row] = 0.f;
        return;
    }
    float lsum = 0.f;
    #pragma unroll
    for (int r = 0; r < 16; ++r) {
        s0[r] = __expf(s0[r] - m);
        s1[r] = __expf(s1[r] - m);
        lsum += s0[r] + s1[r];
    }
    #pragma unroll
    for (int off = 1; off < 64; off <<= 1) lsum += __shfl_xor(lsum, off);
    float invl = 1.0f / lsum;
    #pragma unroll
    for (int r = 0; r < 16; ++r) {
        unsigned lo = (unsigned)f2bf(s0[r] * invl);
        unsigned hi = (unsigned)f2bf(s1[r] * invl);
        arow32[ln + 64 * r] = lo | (hi << 16);
    }
    if (ln == 0) out[(size_t)B * T * D + row] = 1.0f;
}

// Split-K GEMM (NSPLIT=2, one launch) — R13 proven structure.
// BM=128, BN=128, BK=64; 4 waves (2x2); depth-2 counted-vmcnt dbuf (64KB LDS, 2 blk/CU);
// XCD-group mapping g = bid&7 owns (t-quadrant, K-half); bf16 partials.
__global__ __launch_bounds__(256, 2) void k_gemm(const ushort_t* __restrict__ attn,
        const ushort_t* __restrict__ fT, ushort_t* __restrict__ partial) {
    __shared__ __align__(16) ushort_t As[2 * 8192];
    __shared__ __align__(16) ushort_t Bs[2 * 8192];
    const int tid = threadIdx.x;
    const int lane = tid & 63, wid = tid >> 6;      // wid 0..3
    const int wm = wid >> 1, wn = wid & 1;          // 2 x 2 wave grid

    const int bid = blockIdx.x;
    const int g = bid & 7;                          // XCD group
    const int i6 = bid >> 3;                        // 0..47
    const int tq = g & 3;                           // t-quadrant
    const int s = g >> 2;                           // K-half
    const int b = i6 & 7;
    const int n0 = (i6 >> 3) * 128;                 // 0..5
    const int t0 = tq * 128;
    const int kbase = s * KSPLIT;

    const ushort_t* Ab = attn + ((size_t)b * T + t0) * P + kbase;
    const ushort_t* Bb = fT + ((size_t)b * D + n0) * P + kbase;

    const int rl8 = lane >> 3;               // row within 8-row chunk
    const int slot = (lane & 7) ^ rl8;       // pre-swizzled 16B slot in global row

    f32x4v acc[4][4];
    #pragma unroll
    for (int i = 0; i < 4; ++i)
        #pragma unroll
        for (int j = 0; j < 4; ++j)
            acc[i][j] = (f32x4v){0.f, 0.f, 0.f, 0.f};

    const int lr = lane & 15, hi4 = lane >> 4;

    #define STAGE(buf, kt) do { \
        const ushort_t* a_src = Ab + (size_t)(kt) * 64; \
        const ushort_t* b_src = Bb + (size_t)(kt) * 64; \
        _Pragma("unroll") \
        for (int i = 0; i < 4; ++i) { \
            int c = wid * 4 + i; \
            GLD16(a_src + (size_t)(c * 8 + rl8) * P + slot * 8, &As[(buf) * 8192 + c * 512]); \
        } \
        _Pragma("unroll") \
        for (int i = 0; i < 4; ++i) { \
            int c = wid * 4 + i; \
            GLD16(b_src + (size_t)(c * 8 + rl8) * P + slot * 8, &Bs[(buf) * 8192 + c * 512]); \
        } \
    } while (0)

    // swizzled LDS read address (ushort units) for (row, 16B-slot kslot)
    #define LDA(row, kslot) (((row) >> 3) * 512 + ((row) & 7) * 64 + (((kslot) ^ ((row) & 7)) * 8))

    #define COMPUTE(buf) do { \
        _Pragma("unroll") \
        for (int ks = 0; ks < 2; ++ks) { \
            short8 a[4], bfr[4]; \
            int kslot = ks * 4 + hi4; \
            _Pragma("unroll") \
            for (int i = 0; i < 4; ++i) \
                a[i] = *(const short8*)&As[(buf) * 8192 + LDA(wm * 64 + i * 16 + lr, kslot)]; \
            _Pragma("unroll") \
            for (int j = 0; j < 4; ++j) \
                bfr[j] = *(const short8*)&Bs[(buf) * 8192 + LDA(wn * 64 + j * 16 + lr, kslot)]; \
            _Pragma("unroll") \
            for (int i = 0; i < 4; ++i) \
                _Pragma("unroll") \
                for (int j = 0; j < 4; ++j) \
                    acc[i][j] = __builtin_amdgcn_mfma_f32_16x16x32_bf16(a[i], bfr[j], acc[i][j], 0, 0, 0); \
        } \
    } while (0)

    STAGE(0, 0);
    int cur = 0;
    for (int kt = 0; kt < KSPLIT / 64 - 1; ++kt) {
        STAGE(cur ^ 1, kt + 1);
        asm volatile("s_waitcnt vmcnt(8)" ::: "memory");    // prev buffer's 8 loads retired
        RAW_BARRIER();
        COMPUTE(cur);
        RAW_BARRIER();                                      // WAR before next STAGE overwrite
        cur ^= 1;
    }
    asm volatile("s_waitcnt vmcnt(0)" ::: "memory");
    RAW_BARRIER();
    COMPUTE(cur);

    ushort_t* pout = partial + (size_t)s * B * T * D;
    #pragma unroll
    for (int i = 0; i < 4; ++i) {
        #pragma unroll
        for (int j = 0; j < 4; ++j) {
            int trow = t0 + wm * 64 + i * 16 + hi4 * 4;
            int ncol = n0 + wn * 64 + j * 16 + lr;
            #pragma unroll
            for (int q = 0; q < 4; ++q)
                pout[((size_t)(b * T) + trow + q) * D + ncol] = f2bf(acc[i][j][q]);
        }
    }
    #undef STAGE
    #undef LDA
    #undef COMPUTE
}

// fixed-order reduction of the 2 bf16 K-split partials (deterministic)
__global__ __launch_bounds__(256) void k_reduce(const ushort_t* __restrict__ partial,
                                                float* __restrict__ out) {
    const size_t i = (size_t)blockIdx.x * 256 + threadIdx.x;   // uint4 index (8 bf16)
    const size_t stride = (size_t)(B * T * D) / 8;
    const uint4* p = (const uint4*)partial;
    uint4 a = p[i], b2 = p[i + stride];
    float4 r0, r1;
    r0.x = __uint_as_float(a.x << 16)          + __uint_as_float(b2.x << 16);
    r0.y = __uint_as_float(a.x & 0xffff0000u)  + __uint_as_float(b2.x & 0xffff0000u);
    r0.z = __uint_as_float(a.y << 16)          + __uint_as_float(b2.y << 16);
    r0.w = __uint_as_float(a.y & 0xffff0000u)  + __uint_as_float(b2.y & 0xffff0000u);
    r1.x = __uint_as_float(a.z << 16)          + __uint_as_float(b2.z << 16);
    r1.y = __uint_as_float(a.z & 0xffff0000u)  + __uint_as_float(b2.z & 0xffff0000u);
    r1.z = __uint_as_float(a.w << 16)          + __uint_as_float(b2.w << 16);
    r1.w = __uint_as_float(a.w & 0xffff0000u)  + __uint_as_float(b2.w & 0xffff0000u);
    ((float4*)out)[2 * i]     = r0;
    ((float4*)out)[2 * i + 1] = r1;
}

// ---------------- fallback path (round-1, known-good) ----------------
__global__ __launch_bounds__(256) void k_scores_fb(
        const float* __restrict__ feats, const float* __restrict__ pboxes,
        const float* __restrict__ w, const float* __restrict__ bias,
        float* __restrict__ ws) {
    int row = blockIdx.x * 4 + (threadIdx.x >> 6);
    int lane = threadIdx.x & 63;
    const float* f = feats + (size_t)row * D;
    float acc = 0.f;
    #pragma unroll
    for (int k = 0; k < D / 64; ++k) acc += f[lane + k * 64] * w[lane + k * 64];
    #pragma unroll
    for (int off = 1; off < 64; off <<= 1) acc += __shfl_xor(acc, off);
    if (lane == 0) {
        ws[IDX_SCORES + row] = acc + bias[0];
        ws[IDX_CX + row] = 0.5f * (pboxes[row * 4 + 0] + pboxes[row * 4 + 2]);
        ws[IDX_CY + row] = 0.5f * (pboxes[row * 4 + 1] + pboxes[row * 4 + 3]);
    }
}

__global__ __launch_bounds__(256) void k_main_fb(
        const float* __restrict__ feats, const float* __restrict__ tboxes,
        const unsigned char* __restrict__ mask8,
        const float* __restrict__ ws, float* __restrict__ out) {
    const int t = blockIdx.x, b = blockIdx.y;
    const int tid = threadIdx.x;
    const float scale = ws[IDX_SCALE];
    const float* scores = ws + IDX_SCORES;
    const float* cxs = ws + IDX_CX;
    const float* cys = ws + IDX_CY;
    const int row = b * T + t;
    const float lo_x = tboxes[row * 4 + 0] * scale;
    const float lo_y = tboxes[row * 4 + 1] * scale;
    const float hi_x = tboxes[row * 4 + 2] * scale;
    const float hi_y = tboxes[row * 4 + 3] * scale;
    bool storage_u8 = ((mask8[1] | mask8[2] | mask8[3]) != 0);
    bool tmask = storage_u8 ? (mask8[row] != 0) : (((const int*)mask8)[row] != 0);
    float s[8]; bool ib[8];
    float m = -1e30f;
    #pragma unroll
    for (int j = 0; j < 8; ++j) {
        int p = tid + j * 256;
        float cx = cxs[b * P + p], cy = cys[b * P + p];
        bool in = (cx >= lo_x) && (cx <= hi_x) && (cy >= lo_y) && (cy <= hi_y);
        ib[j] = in;
        s[j] = scores[b * P + p];
        if (in) m = fmaxf(m, s[j]);
    }
    __shared__ float s_red[4];
    #pragma unroll
    for (int off = 1; off < 64; off <<= 1) m = fmaxf(m, __shfl_xor(m, off));
    if ((tid & 63) == 0) s_red[tid >> 6] = m;
    __syncthreads();
    float mb = fmaxf(fmaxf(s_red[0], s_red[1]), fmaxf(s_red[2], s_red[3]));
    bool any = mb > -1e29f;
    const size_t obase = (size_t)row * D;
    if (!any || !tmask) {
        out[obase + tid] = 0.f; out[obase + tid + 256] = 0.f; out[obase + tid + 512] = 0.f;
        if (tid == 0) out[(size_t)B * T * D + row] = 0.f;
        return;
    }
    float w8[8]; int c = 0; float lsum = 0.f;
    #pragma unroll
    for (int j = 0; j < 8; ++j) {
        float wv = ib[j] ? __expf(s[j] - mb) : 0.f;
        w8[j] = wv; lsum += wv;
        if (ib[j]) ++c;
    }
    __shared__ float s_sum[4];
    #pragma unroll
    for (int off = 1; off < 64; off <<= 1) lsum += __shfl_xor(lsum, off);
    if ((tid & 63) == 0) s_sum[tid >> 6] = lsum;
    __syncthreads();
    float l = s_sum[0] + s_sum[1] + s_sum[2] + s_sum[3];
    __shared__ int s_cnt[256];
    s_cnt[tid] = c;
    __syncthreads();
    #pragma unroll
    for (int off = 1; off < 256; off <<= 1) {
        int v = (tid >= off) ? s_cnt[tid - off] : 0;
        __syncthreads();
        s_cnt[tid] += v;
        __syncthreads();
    }
    int excl = s_cnt[tid] - c;
    int nnz = s_cnt[255];
    __shared__ int s_idx[P];
    __shared__ float s_wt[P];
    int o = excl;
    #pragma unroll
    for (int j = 0; j < 8; ++j) {
        if (ib[j]) { s_idx[o] = tid + j * 256; s_wt[o] = w8[j]; ++o; }
    }
    __syncthreads();
    float a0 = 0.f, a1 = 0.f, a2 = 0.f;
    const float* fb = feats + (size_t)b * P * D;
    for (int i = 0; i < nnz; ++i) {
        int p = s_idx[i];
        float wv = s_wt[i];
        const float* fr = fb + (size_t)p * D + tid;
        a0 += wv * fr[0]; a1 += wv * fr[256]; a2 += wv * fr[512];
    }
    float inv = 1.0f / l;
    out[obase + tid] = a0 * inv;
    out[obase + tid + 256] = a1 * inv;
    out[obase + tid + 512] = a2 * inv;
    if (tid == 0) out[(size_t)B * T * D + row] = 1.0f;
}

extern "C" void kernel_launch(void* const* d_in, const int* in_sizes, int n_in,
                              void* d_out, int out_size, void* d_ws, size_t ws_size,
                              hipStream_t stream) {
    const float* feats  = (const float*)d_in[0];
    const float* tboxes = (const float*)d_in[1];
    const float* pboxes = (const float*)d_in[2];
    const unsigned char* tmask = (const unsigned char*)d_in[3];
    const float* w      = (const float*)d_in[4];
    const float* bias   = (const float*)d_in[5];
    float* out = (float*)d_out;
    float* ws  = (float*)d_ws;

    if (ws_size >= WS_NEED) {
        ushort_t* attn = (ushort_t*)((char*)d_ws + OFF_ATTN_BYTES);
        ushort_t* fT   = (ushort_t*)((char*)d_ws + OFF_FT_BYTES);
        ushort_t* part = (ushort_t*)((char*)d_ws + OFF_PART_BYTES);
        k_prep<<<dim3(P / 64, 2, B), 256, 0, stream>>>(feats, w, tboxes, ws, fT);
        k_attn<<<dim3(T / 4, B), 256, 0, stream>>>(tboxes, pboxes, tmask, bias, ws, attn, out);
        k_gemm<<<dim3(NSPLIT * B * (T / 128) * (D / 128)), 256, 0, stream>>>(attn, fT, part);
        k_reduce<<<dim3(B * T * D / 8 / 256), 256, 0, stream>>>(part, out);
    } else {
        k_scale<<<1, 256, 0, stream>>>(tboxes, ws);
        k_scores_fb<<<(B * P) / 4, 256, 0, stream>>>(feats, pboxes, w, bias, ws);
        k_main_fb<<<dim3(T, B), 256, 0, stream>>>(feats, tboxes, tmask, ws, out);
    }
}